// Round 1
// baseline (702.198 us; speedup 1.0000x reference)
//
#include <hip/hip_runtime.h>
#include <stdint.h>

typedef __bf16   bf16x8 __attribute__((ext_vector_type(8)));
typedef float    f32x4  __attribute__((ext_vector_type(4)));
typedef uint16_t u16x8  __attribute__((ext_vector_type(8)));

__device__ __forceinline__ uint16_t f2bf(float f) {
  uint32_t b = __builtin_bit_cast(uint32_t, f);
  b += 0x7fffu + ((b >> 16) & 1u);
  return (uint16_t)(b >> 16);
}
__device__ __forceinline__ float bf2f(uint16_t u) {
  return __builtin_bit_cast(float, ((uint32_t)u) << 16);
}
// load 8 contiguous fp32, round to bf16x8 (for fused cast during LDS staging)
__device__ __forceinline__ u16x8 ldcvt8(const float* __restrict__ p) {
  f32x4 lo = *(const f32x4*)p;
  f32x4 hi = *(const f32x4*)(p + 4);
  u16x8 o;
  o[0] = f2bf(lo[0]); o[1] = f2bf(lo[1]); o[2] = f2bf(lo[2]); o[3] = f2bf(lo[3]);
  o[4] = f2bf(hi[0]); o[5] = f2bf(hi[1]); o[6] = f2bf(hi[2]); o[7] = f2bf(hi[3]);
  return o;
}

// address-space-qualified typedefs for global_load_lds
typedef const __attribute__((address_space(1))) uint32_t cga_u32;
typedef __attribute__((address_space(3))) uint32_t lds_u32;
__device__ __forceinline__ void gload16(const uint16_t* g, uint16_t* l) {
  // 16B per lane, direct global->LDS DMA (no VGPR round-trip, no VALU)
  __builtin_amdgcn_global_load_lds((cga_u32*)g, (lds_u32*)l, 16, 0, 0);
}

// ---------------- fp32 -> bf16 cast (memory-bound, vectorized) ----------------
__global__ __launch_bounds__(256) void cast_kernel(const float* __restrict__ in,
                                                   uint16_t* __restrict__ out, int n8) {
  int i = blockIdx.x * 256 + threadIdx.x;
  if (i >= n8) return;
  u16x8 o = ldcvt8(in + (size_t)i * 8);
  *(u16x8*)(out + (size_t)i * 8) = o;
}

// ---------------- copy both caches (input caches -> output regions) ----------------
__global__ __launch_bounds__(256) void copy2_kernel(const float* __restrict__ a, float* __restrict__ da,
                                                    const float* __restrict__ b, float* __restrict__ db,
                                                    int n4) {
  int i = blockIdx.x * 256 + threadIdx.x;
  if (i >= n4) return;
  *(f32x4*)(da + (size_t)i * 4) = *(const f32x4*)(a + (size_t)i * 4);
  *(f32x4*)(db + (size_t)i * 4) = *(const f32x4*)(b + (size_t)i * 4);
}

// ---------------- bf16 NT GEMM, m97 structure ----------------
// C[M][N] = sum_k A[m][k]*B[n][k]; A,B bf16 row-major-along-K.
// 128x128 tile, BK=32, 256 thr (4 waves 2x2, wave = 64x64 via 4x4 16x16x32 mfma).
// Staging via global_load_lds width-16 into LINEAR LDS (wave-uniform base + lane*16).
template <int OUT_BF16>
__global__ __launch_bounds__(256) void gemm_nt_bf16(const uint16_t* __restrict__ A,
                                                    const uint16_t* __restrict__ B,
                                                    void* __restrict__ Cout,
                                                    int M, int N, int K) {
  __shared__ __align__(16) uint16_t As[128 * 32];
  __shared__ __align__(16) uint16_t Bs[128 * 32];
  const int tid = threadIdx.x;
  const int lane = tid & 63, wave = tid >> 6;
  const int l16 = lane & 15, quad = lane >> 4;
  const int wm = (wave & 1) << 6, wn = (wave >> 1) << 6;
  const int bm = blockIdx.y, bn = blockIdx.x;

  f32x4 acc[4][4] = {};

  // staging map: wave w, lane l -> LDS byte (w*1024 + l*16) == row (w*16 + l/4), chunk (l&3)
  const int srow = wave * 16 + (lane >> 2);
  const int schunk = lane & 3;
  const uint16_t* Ag = A + (size_t)(bm * 128 + srow) * K + schunk * 8;
  const uint16_t* Bg = B + (size_t)(bn * 128 + srow) * K + schunk * 8;
  const size_t rs64 = (size_t)64 * K;
  uint16_t* AsD0 = &As[srow * 32 + schunk * 8];
  uint16_t* AsD1 = AsD0 + 64 * 32;
  uint16_t* BsD0 = &Bs[srow * 32 + schunk * 8];
  uint16_t* BsD1 = BsD0 + 64 * 32;

  for (int k0 = 0; k0 < K; k0 += 32) {
    gload16(Ag, AsD0);
    gload16(Ag + rs64, AsD1);
    gload16(Bg, BsD0);
    gload16(Bg + rs64, BsD1);
    Ag += 32; Bg += 32;
    __syncthreads();  // compiler emits vmcnt(0) drain -> staged data visible
    bf16x8 af[4], bfr[4];
#pragma unroll
    for (int i = 0; i < 4; i++) {
      af[i]  = __builtin_bit_cast(bf16x8, *(const u16x8*)&As[(wm + i * 16 + l16) * 32 + quad * 8]);
      bfr[i] = __builtin_bit_cast(bf16x8, *(const u16x8*)&Bs[(wn + i * 16 + l16) * 32 + quad * 8]);
    }
#pragma unroll
    for (int i = 0; i < 4; i++)
#pragma unroll
      for (int j = 0; j < 4; j++)
        acc[i][j] = __builtin_amdgcn_mfma_f32_16x16x32_bf16(af[i], bfr[j], acc[i][j], 0, 0, 0);
    __syncthreads();  // lgkmcnt(0) drain -> safe to overwrite LDS next iter
  }

  // C/D layout: row = quad*4 + reg, col = l16 (m89-verified)
  const int row0 = bm * 128 + wm + quad * 4;
  const int col0 = bn * 128 + wn + l16;
#pragma unroll
  for (int i = 0; i < 4; i++)
#pragma unroll
    for (int j = 0; j < 4; j++)
#pragma unroll
      for (int r = 0; r < 4; r++) {
        size_t idx = (size_t)(row0 + i * 16 + r) * N + (col0 + j * 16);
        if constexpr (OUT_BF16) ((uint16_t*)Cout)[idx] = f2bf(acc[i][j][r]);
        else                    ((float*)Cout)[idx]    = acc[i][j][r];
      }
}

// ---------------- fallback NT GEMM (fused fp32 cast, reg-staged) ----------------
template <int A_BF16, int OUT_BF16>
__global__ __launch_bounds__(256) void gemm_bt(const void* __restrict__ Ap,
                                               const float* __restrict__ B,
                                               void* __restrict__ Cout, int M, int N, int K) {
  constexpr int PAD = 40;  // 80B row stride -> 2-way bank aliasing only (free per m136)
  __shared__ __align__(16) uint16_t As[128 * PAD];
  __shared__ __align__(16) uint16_t Bs[128 * PAD];
  const int tid = threadIdx.x;
  const int lane = tid & 63, wave = tid >> 6;
  const int l16 = lane & 15, quad = lane >> 4;
  const int wm = (wave & 1) << 6, wn = (wave >> 1) << 6;
  const int bm = blockIdx.y, bn = blockIdx.x;

  f32x4 acc[4][4] = {};

  const int srow = tid >> 2;        // 0..63
  const int scol = (tid & 3) << 3;  // 0,8,16,24
  const size_t aoff = (size_t)(bm * 128 + srow) * K + scol;
  const uint16_t* Agh = (const uint16_t*)Ap + aoff;
  const float*    Agf = (const float*)Ap + aoff;
  const float*    Bg  = B + (size_t)(bn * 128 + srow) * K + scol;
  const size_t rstride = (size_t)64 * K;

  for (int k0 = 0; k0 < K; k0 += 32) {
    u16x8 a0, a1;
    if constexpr (A_BF16) {
      a0 = *(const u16x8*)Agh;
      a1 = *(const u16x8*)(Agh + rstride);
      Agh += 32;
    } else {
      a0 = ldcvt8(Agf);
      a1 = ldcvt8(Agf + rstride);
      Agf += 32;
    }
    u16x8 b0 = ldcvt8(Bg);
    u16x8 b1 = ldcvt8(Bg + rstride);
    Bg += 32;
    __syncthreads();
    *(u16x8*)&As[srow * PAD + scol] = a0;
    *(u16x8*)&As[(srow + 64) * PAD + scol] = a1;
    *(u16x8*)&Bs[srow * PAD + scol] = b0;
    *(u16x8*)&Bs[(srow + 64) * PAD + scol] = b1;
    __syncthreads();
    bf16x8 af[4], bfr[4];
#pragma unroll
    for (int i = 0; i < 4; i++) {
      af[i]  = __builtin_bit_cast(bf16x8, *(const u16x8*)&As[(wm + i * 16 + l16) * PAD + quad * 8]);
      bfr[i] = __builtin_bit_cast(bf16x8, *(const u16x8*)&Bs[(wn + i * 16 + l16) * PAD + quad * 8]);
    }
#pragma unroll
    for (int i = 0; i < 4; i++)
#pragma unroll
      for (int j = 0; j < 4; j++)
        acc[i][j] = __builtin_amdgcn_mfma_f32_16x16x32_bf16(af[i], bfr[j], acc[i][j], 0, 0, 0);
  }

  const int row0 = bm * 128 + wm + quad * 4;
  const int col0 = bn * 128 + wn + l16;
#pragma unroll
  for (int i = 0; i < 4; i++)
#pragma unroll
    for (int j = 0; j < 4; j++)
#pragma unroll
      for (int r = 0; r < 4; r++) {
        size_t idx = (size_t)(row0 + i * 16 + r) * N + (col0 + j * 16);
        if constexpr (OUT_BF16) ((uint16_t*)Cout)[idx] = f2bf(acc[i][j][r]);
        else                    ((float*)Cout)[idx]    = acc[i][j][r];
      }
}

// ---------------- RoPE + cache scatter + attention-buffer emit ----------------
__global__ __launch_bounds__(256) void rope_kernel(const uint16_t* __restrict__ xqkv,
    const float* __restrict__ cosf, const float* __restrict__ sinf,
    const int* __restrict__ pos,
    uint16_t* __restrict__ qb, uint16_t* __restrict__ kb, uint16_t* __restrict__ vb,
    float* __restrict__ ck, float* __restrict__ cv) {
  const int s = blockIdx.x;
  const int e0 = (blockIdx.y * 256 + threadIdx.x) * 8;  // 0..6136
  const int head = e0 >> 7;
  const int d0 = e0 & 127;
  u16x8 u = *(const u16x8*)(xqkv + (size_t)s * 6144 + e0);
  float x[8];
#pragma unroll
  for (int j = 0; j < 8; j++) x[j] = bf2f(u[j]);

  if (head < 40) {  // rope for q heads (0..31) and k heads (32..39)
    const int i0 = d0 >> 1;
    f32x4 c4 = *(const f32x4*)(cosf + (size_t)s * 64 + i0);
    f32x4 s4 = *(const f32x4*)(sinf + (size_t)s * 64 + i0);
    float o[8];
#pragma unroll
    for (int kk = 0; kk < 4; kk++) {
      float x1 = x[2 * kk], x2 = x[2 * kk + 1];
      o[2 * kk]     = x1 * c4[kk] - x2 * s4[kk];
      o[2 * kk + 1] = x1 * s4[kk] + x2 * c4[kk];
    }
    u16x8 ob;
#pragma unroll
    for (int j = 0; j < 8; j++) ob[j] = f2bf(o[j]);
    if (head < 32) {
      *(u16x8*)(qb + (size_t)s * 4096 + head * 128 + d0) = ob;
    } else {
      int kvh = head - 32;
      *(u16x8*)(kb + ((size_t)kvh * 2048 + s) * 128 + d0) = ob;
      int p = pos[s];
      if ((unsigned)p < 4096u) {
        float* dst = ck + ((size_t)p * 8 + kvh) * 128 + d0;
#pragma unroll
        for (int j = 0; j < 8; j++) dst[j] = o[j];
      }
    }
  } else {  // v heads (40..47), no rope
    int kvh = head - 40;
    *(u16x8*)(vb + ((size_t)kvh * 2048 + s) * 128 + d0) = u;
    int p = pos[s];
    if ((unsigned)p < 4096u) {
      float* dst = cv + ((size_t)p * 8 + kvh) * 128 + d0;
#pragma unroll
      for (int j = 0; j < 8; j++) dst[j] = x[j];
    }
  }
}

// ---------------- V transpose per kv head: [8][2048][128] -> [8][128][2048] ----------------
__global__ __launch_bounds__(256) void vtrans_kernel(const uint16_t* __restrict__ vb,
                                                     uint16_t* __restrict__ vt) {
  __shared__ __align__(16) uint16_t t[32 * 72];
  const int h = blockIdx.z;
  const int s0 = blockIdx.x * 64, d0 = blockIdx.y * 32;
  const uint16_t* in = vb + (size_t)h * 2048 * 128;
  uint16_t* out = vt + (size_t)h * 128 * 2048;
  const int tid = threadIdx.x;
  {
    int r = tid >> 2, c8 = (tid & 3) * 8;
    u16x8 v = *(const u16x8*)(in + (size_t)(s0 + r) * 128 + d0 + c8);
#pragma unroll
    for (int j = 0; j < 8; j++) t[(c8 + j) * 72 + r] = v[j];
  }
  __syncthreads();
  {
    int r = tid >> 3, c8 = (tid & 7) * 8;
    u16x8 v = *(const u16x8*)&t[r * 72 + c8];
    *(u16x8*)(out + (size_t)(d0 + r) * 2048 + s0 + c8) = v;
  }
}

// ---------------- flash attention (causal; window 4096 >= seqlen so pure causal) ----------------
__global__ __launch_bounds__(256) void flash_kernel(const uint16_t* __restrict__ Qb,
    const uint16_t* __restrict__ Kb, const uint16_t* __restrict__ Vtb,
    uint16_t* __restrict__ Ob) {
  constexpr int QP = 136, KP = 136, VP = 72, PP = 72;
  __shared__ __align__(16) uint16_t Qs[64 * QP];
  __shared__ __align__(16) uint16_t Ks[64 * KP];
  __shared__ __align__(16) uint16_t Vts[128 * VP];
  __shared__ __align__(16) uint16_t Ps[4][16 * PP];
  const int tid = threadIdx.x;
  const int lane = tid & 63, wave = tid >> 6;
  const int l16 = lane & 15, quad = lane >> 4;
  const int qb = blockIdx.x * 64;
  const int h = blockIdx.y, kvh = h >> 2;
  const uint16_t* Qg = Qb + (size_t)qb * 4096 + h * 128;
  const uint16_t* Kg = Kb + (size_t)kvh * 2048 * 128;
  const uint16_t* Vg = Vtb + (size_t)kvh * 128 * 2048;

#pragma unroll
  for (int i = 0; i < 4; i++) {
    int c = tid + i * 256;
    int r = c >> 4, c8 = (c & 15) * 8;
    *(u16x8*)&Qs[r * QP + c8] = *(const u16x8*)(Qg + (size_t)r * 4096 + c8);
  }
  __syncthreads();
  bf16x8 qf[4];
#pragma unroll
  for (int dc = 0; dc < 4; dc++)
    qf[dc] = __builtin_bit_cast(bf16x8, *(const u16x8*)&Qs[(wave * 16 + l16) * QP + dc * 32 + quad * 8]);

  f32x4 oacc[8] = {};
  float m_run[4], l_run[4];
#pragma unroll
  for (int r = 0; r < 4; r++) { m_run[r] = -1e30f; l_run[r] = 0.f; }
  const float scale = 0.08838834764831845f;  // 128^-0.5
  const int nch = blockIdx.x + 1;

  for (int ch = 0; ch < nch; ch++) {
    const int cb = ch * 64;
    __syncthreads();
#pragma unroll
    for (int i = 0; i < 4; i++) {
      int c = tid + i * 256;
      int r = c >> 4, c8 = (c & 15) * 8;
      *(u16x8*)&Ks[r * KP + c8] = *(const u16x8*)(Kg + (size_t)(cb + r) * 128 + c8);
    }
#pragma unroll
    for (int i = 0; i < 4; i++) {
      int c = tid + i * 256;
      int r = c >> 3, c8 = (c & 7) * 8;
      *(u16x8*)&Vts[r * VP + c8] = *(const u16x8*)(Vg + (size_t)r * 2048 + cb + c8);
    }
    __syncthreads();

    f32x4 sacc[4] = {};
#pragma unroll
    for (int ni = 0; ni < 4; ni++)
#pragma unroll
      for (int dc = 0; dc < 4; dc++) {
        bf16x8 kf = __builtin_bit_cast(bf16x8,
            *(const u16x8*)&Ks[(ni * 16 + l16) * KP + dc * 32 + quad * 8]);
        sacc[ni] = __builtin_amdgcn_mfma_f32_16x16x32_bf16(qf[dc], kf, sacc[ni], 0, 0, 0);
      }

    float p[4][4], alpha[4];
#pragma unroll
    for (int reg = 0; reg < 4; reg++) {
      const int q = qb + wave * 16 + quad * 4 + reg;
      float mx = -1e30f;
#pragma unroll
      for (int ni = 0; ni < 4; ni++) {
        float sv = sacc[ni][reg] * scale;
        if (cb + ni * 16 + l16 > q) sv = -1e30f;  // causal mask
        p[ni][reg] = sv;
        mx = fmaxf(mx, sv);
      }
#pragma unroll
      for (int off = 8; off >= 1; off >>= 1)
        mx = fmaxf(mx, __shfl_xor(mx, off, 64));
      float mn = fmaxf(m_run[reg], mx);
      alpha[reg] = __expf(m_run[reg] - mn);
      m_run[reg] = mn;
      float rs = 0.f;
#pragma unroll
      for (int ni = 0; ni < 4; ni++) {
        float e = __expf(p[ni][reg] - mn);
        p[ni][reg] = e;
        rs += e;
      }
#pragma unroll
      for (int off = 8; off >= 1; off >>= 1)
        rs += __shfl_xor(rs, off, 64);
      l_run[reg] = l_run[reg] * alpha[reg] + rs;
    }

#pragma unroll
    for (int dt = 0; dt < 8; dt++)
#pragma unroll
      for (int reg = 0; reg < 4; reg++)
        oacc[dt][reg] *= alpha[reg];

    uint16_t* Pw = Ps[wave];
#pragma unroll
    for (int ni = 0; ni < 4; ni++)
#pragma unroll
      for (int reg = 0; reg < 4; reg++)
        Pw[(quad * 4 + reg) * PP + ni * 16 + l16] = f2bf(p[ni][reg]);

    bf16x8 pf[2];
#pragma unroll
    for (int kc = 0; kc < 2; kc++)
      pf[kc] = __builtin_bit_cast(bf16x8, *(const u16x8*)&Pw[l16 * PP + kc * 32 + quad * 8]);

#pragma unroll
    for (int dt = 0; dt < 8; dt++)
#pragma unroll
      for (int kc = 0; kc < 2; kc++) {
        bf16x8 vf = __builtin_bit_cast(bf16x8,
            *(const u16x8*)&Vts[(dt * 16 + l16) * VP + kc * 32 + quad * 8]);
        oacc[dt] = __builtin_amdgcn_mfma_f32_16x16x32_bf16(pf[kc], vf, oacc[dt], 0, 0, 0);
      }
  }

#pragma unroll
  for (int dt = 0; dt < 8; dt++)
#pragma unroll
    for (int reg = 0; reg < 4; reg++) {
      float o = oacc[dt][reg] / l_run[reg];
      int row = qb + wave * 16 + quad * 4 + reg;
      int col = h * 128 + dt * 16 + l16;
      Ob[(size_t)row * 4096 + col] = f2bf(o);
    }
}

extern "C" void kernel_launch(void* const* d_in, const int* in_sizes, int n_in,
                              void* d_out, int out_size, void* d_ws, size_t ws_size,
                              hipStream_t stream) {
  const float* x     = (const float*)d_in[0];
  const float* cosf  = (const float*)d_in[1];
  const float* sinf  = (const float*)d_in[2];
  const int*   pos   = (const int*)d_in[3];
  // d_in[4] (mask) unused: window 4096 > max distance 2047 => pure causal, computed analytically
  const float* ck_in = (const float*)d_in[5];
  const float* cv_in = (const float*)d_in[6];
  const float* Wqkv  = (const float*)d_in[7];
  const float* Wo    = (const float*)d_in[8];

  float* out    = (float*)d_out;                    // [2048][4096]
  float* ck_out = out + (size_t)2048 * 4096;        // [4096][8][128]
  float* cv_out = ck_out + (size_t)4096 * 8 * 128;  // [4096][8][128]

  char* ws = (char*)d_ws;

  if (ws_size >= 104857600ull) {
    // bf16-precast path (100 MB ws):
    //   [0,24M)    xqkv_bf [2048][6144]; reused as attn-out bf16 [2048][4096] after rope
    //   [24,40M)   x_bf [2048][4096] (dead after gemm1), then q_bf overlay
    //   [40,44M)   k_bf [8][2048][128]
    //   [44,48M)   v_bf [8][2048][128]
    //   [48,52M)   vt_bf [8][128][2048]
    //   [52,100M)  Wqkv_bf [6144][4096] (dead after gemm1), then Wo_bf overlay
    uint16_t* xqkv_bf = (uint16_t*)(ws);
    uint16_t* attn_bf = (uint16_t*)(ws);
    uint16_t* x_bf    = (uint16_t*)(ws + 25165824);
    uint16_t* q_bf    = (uint16_t*)(ws + 25165824);  // overlays x_bf (dead after gemm1)
    uint16_t* k_bf    = (uint16_t*)(ws + 41943040);
    uint16_t* v_bf    = (uint16_t*)(ws + 46137344);
    uint16_t* vt_bf   = (uint16_t*)(ws + 50331648);
    uint16_t* wq_bf   = (uint16_t*)(ws + 54525952);
    uint16_t* wo_bf   = (uint16_t*)(ws + 54525952);  // overlays wq_bf (dead after gemm1)

    cast_kernel<<<4096, 256, 0, stream>>>(x, x_bf, 1048576);        // 2048*4096/8
    cast_kernel<<<12288, 256, 0, stream>>>(Wqkv, wq_bf, 3145728);   // 6144*4096/8

    // xqkv = x @ Wqkv^T  (M=2048, N=6144, K=4096), all bf16, gload_lds staging
    gemm_nt_bf16<1><<<dim3(48, 16), 256, 0, stream>>>(x_bf, wq_bf, xqkv_bf, 2048, 6144, 4096);

    copy2_kernel<<<4096, 256, 0, stream>>>(ck_in, ck_out, cv_in, cv_out, 1048576);

    rope_kernel<<<dim3(2048, 3), 256, 0, stream>>>(xqkv_bf, cosf, sinf, pos,
                                                   q_bf, k_bf, v_bf, ck_out, cv_out);

    vtrans_kernel<<<dim3(32, 4, 8), 256, 0, stream>>>(v_bf, vt_bf);

    flash_kernel<<<dim3(32, 32), 256, 0, stream>>>(q_bf, k_bf, vt_bf, attn_bf);

    cast_kernel<<<8192, 256, 0, stream>>>(Wo, wo_bf, 2097152);      // 4096*4096/8

    // out = attn @ Wo^T  (M=2048, N=4096, K=4096), all bf16, fp32 out
    gemm_nt_bf16<0><<<dim3(32, 16), 256, 0, stream>>>(attn_bf, wo_bf, out, 2048, 4096, 4096);
  } else {
    // fallback: previous harness-verified 52 MB path (fused-cast reg-staged GEMMs)
    uint16_t* xqkv_bf = (uint16_t*)(ws);
    uint16_t* attn_bf = (uint16_t*)(ws);
    uint16_t* q_bf    = (uint16_t*)(ws + 25165824);
    uint16_t* k_bf    = (uint16_t*)(ws + 41943040);
    uint16_t* v_bf    = (uint16_t*)(ws + 46137344);
    uint16_t* vt_bf   = (uint16_t*)(ws + 50331648);

    gemm_bt<0, 1><<<dim3(48, 16), 256, 0, stream>>>(x, Wqkv, xqkv_bf, 2048, 6144, 4096);
    copy2_kernel<<<4096, 256, 0, stream>>>(ck_in, ck_out, cv_in, cv_out, 1048576);
    rope_kernel<<<dim3(2048, 3), 256, 0, stream>>>(xqkv_bf, cosf, sinf, pos,
                                                   q_bf, k_bf, v_bf, ck_out, cv_out);
    vtrans_kernel<<<dim3(32, 4, 8), 256, 0, stream>>>(v_bf, vt_bf);
    flash_kernel<<<dim3(32, 32), 256, 0, stream>>>(q_bf, k_bf, vt_bf, attn_bf);
    gemm_bt<1, 0><<<dim3(32, 16), 256, 0, stream>>>(attn_bf, Wo, out, 2048, 4096, 4096);
  }
}